// Round 5
// baseline (669.029 us; speedup 1.0000x reference)
//
#include <hip/hip_runtime.h>
#include <hip/hip_fp16.h>

// RipEncoding, round 5: fp16 pyramid + counting-sorted (spatially binned)
// gather to kill the L2 line-request bottleneck.
//
// ws layout (bytes):
//   [0, 332928000)              fp16 pyramid (10 v x 1020x1020 px x 16 halfs)
//   [332928000, +41943040)      pl    float4[2621440]  (cx,cy,lx,ly) [v*NS+n]
//   [374871040, +10485760)      keys  int[2621440]
//   [385356800, +2621440)       hist  int[655360]
//   [387978240, +4096)          bsum  int[1024]
//   [387982336, +41943040)      spl   float4[2621440]  sorted pl
//   [429925376, +10485760)      sidx  int[2621440]     sorted n
//   end 440411136 < 498083840 (known-available)

#define NV 10
#define FD 16
#define NS 262144          // 2^18
#define PYR_PX 1040400L    // 1020*1020 pixels per vertex
#define PYR_BYTES   332928000L
#define OFF_PL      332928000L
#define OFF_KEYS    374871040L
#define OFF_HIST    385356800L
#define OFF_BSUM    387978240L
#define OFF_SPL     387982336L
#define OFF_SIDX    429925376L
#define NB_KEYS     655360      // 10*8*8*32*32

__constant__ float c_P[NV][2][3] = {
  {{-0.7071067811865476f, 0.7071067811865476f, 0.0f},
   {-0.4082482904638631f,-0.4082482904638631f, 0.8164965809277261f}},
  {{-0.7071067811865476f, 0.7071067811865476f, 0.0f},
   { 0.4082482904638631f, 0.4082482904638631f, 0.8164965809277261f}},
  {{ 0.7071067811865476f, 0.7071067811865476f, 0.0f},
   {-0.4082482904638631f, 0.4082482904638631f, 0.8164965809277261f}},
  {{ 0.7071067811865476f, 0.7071067811865476f, 0.0f},
   { 0.4082482904638631f,-0.4082482904638631f, 0.8164965809277261f}},
  {{-1.0f, 0.0f, 0.0f},
   { 0.0f,-0.3568220897730899f, 0.9341723589627157f}},
  {{-1.0f, 0.0f, 0.0f},
   { 0.0f, 0.3568220897730899f, 0.9341723589627157f}},
  {{ 0.0f, 1.0f, 0.0f},
   {-0.9341723589627157f, 0.0f, 0.3568220897730899f}},
  {{ 0.0f, 1.0f, 0.0f},
   { 0.9341723589627157f, 0.0f, 0.3568220897730899f}},
  {{-0.3568220897730899f, 0.9341723589627157f, 0.0f},
   { 0.0f, 0.0f, 1.0f}},
  {{ 0.3568220897730899f, 0.9341723589627157f, 0.0f},
   { 0.0f, 0.0f, 1.0f}},
};

__constant__ int c_CW[8] = {0, 512, 768, 896, 960, 992, 1008, 1016};

// pixel offset of plane (l1,l2) inside a vertex's pyramid (includes (0,0))
__device__ __forceinline__ long offp(int l1, int l2) {
  return 1020L * (long)c_CW[l1] + (long)(512 >> l1) * (long)c_CW[l2];
}

__device__ __forceinline__ uint2 pack4(float4 f) {
  __half2 h0 = __floats2half2_rn(f.x, f.y);
  __half2 h1 = __floats2half2_rn(f.z, f.w);
  uint2 s;
  s.x = *(unsigned int*)&h0;
  s.y = *(unsigned int*)&h1;
  return s;
}

// ---- pass 1: one block per (v, y) row; all 8 width levels from LDS ----
__global__ __launch_bounds__(256) void build_w(const float* __restrict__ fm,
                                               __half* __restrict__ pyr)
{
  __shared__ float4 lds[512 * 5];   // pixel p, quad fb at lds[p*5+fb]; 40 KB
  int b = blockIdx.x;
  int v = b >> 9, y = b & 511;
  int t = threadIdx.x;
  const float4* src = (const float4*)(fm + ((long)v * 262144L + (long)y * 512) * FD);
  #pragma unroll
  for (int i = 0; i < 8; ++i) {
    int u = t + 256 * i;                        // linear float4 index 0..2047
    float4 d = src[u];
    lds[(u >> 2) * 5 + (u & 3)] = d;
  }
  __syncthreads();
  __half* bv = pyr + (long)v * PYR_PX * FD;
  {                                             // level (0,0): convert row
    uint2* dst = (uint2*)(bv + (long)y * 512 * FD);
    #pragma unroll
    for (int i = 0; i < 8; ++i) {
      int u = t + 256 * i;
      dst[u] = pack4(lds[(u >> 2) * 5 + (u & 3)]);
    }
  }
  #pragma unroll
  for (int l1 = 1; l1 <= 7; ++l1) {
    int W = 512 >> l1;
    int units = W * 4;
    float4 r[4];
    #pragma unroll
    for (int i = 0; i < 4; ++i) {
      int u = t + 256 * i;
      if (u < units) {
        int px = u >> 2, fb = u & 3;
        float4 a = lds[(2 * px) * 5 + fb];
        float4 c = lds[(2 * px + 1) * 5 + fb];
        r[i].x = 0.5f * (a.x + c.x); r[i].y = 0.5f * (a.y + c.y);
        r[i].z = 0.5f * (a.z + c.z); r[i].w = 0.5f * (a.w + c.w);
      }
    }
    __syncthreads();
    uint2* dst = (uint2*)(bv + (offp(l1, 0) + (long)y * W) * FD);
    #pragma unroll
    for (int i = 0; i < 4; ++i) {
      int u = t + 256 * i;
      if (u < units) {
        int px = u >> 2, fb = u & 3;
        lds[px * 5 + fb] = r[i];
        dst[u] = pack4(r[i]);
      }
    }
    __syncthreads();
  }
}

// ---- pass 2: per-level height pool, fully coalesced (7 launches) ----
__global__ __launch_bounds__(256) void pool_h(__half* __restrict__ pyr, int l2)
{
  int H = 512 >> l2;
  int total = NV * H * 2040;          // units: 1020 px * 2 slots per virtual row
  int t = blockIdx.x * 256 + threadIdx.x;
  if (t >= total) return;
  int u = t % 2040;
  int r2 = t / 2040;
  int c = u >> 1, k = u & 1;          // virtual column, 16B slot
  int y = r2 & (H - 1);
  int v = r2 >> (9 - l2);
  int l1 = 0;
  #pragma unroll
  for (int i = 1; i < 8; ++i) l1 += (c >= c_CW[i]) ? 1 : 0;
  int x = c - c_CW[l1];
  int W = 512 >> l1;
  __half* bv = pyr + (long)v * PYR_PX * FD;
  const __half* src = bv + offp(l1, l2 - 1) * FD;
  uint4 a = *(const uint4*)(src + ((long)(2 * y) * W + x) * FD + k * 8);
  uint4 b = *(const uint4*)(src + ((long)(2 * y + 1) * W + x) * FD + k * 8);
  const __half2* ha = (const __half2*)&a;
  const __half2* hb = (const __half2*)&b;
  uint4 res;
  __half2* hr = (__half2*)&res;
  #pragma unroll
  for (int j = 0; j < 4; ++j) {
    float2 fa = __half22float2(ha[j]);
    float2 fb = __half22float2(hb[j]);
    hr[j] = __floats2half2_rn(0.5f * (fa.x + fb.x), 0.5f * (fa.y + fb.y));
  }
  *(uint4*)(bv + offp(l1, l2) * FD + ((long)y * W + x) * FD + k * 8) = res;
}

// ---- zero the histogram ----
__global__ __launch_bounds__(256) void zero_hist(int* __restrict__ hist)
{
  int i = blockIdx.x * 256 + threadIdx.x;
  if (i < NB_KEYS) hist[i] = 0;
}

// ---- projection + level + key + histogram: one thread per sample ----
__global__ __launch_bounds__(256) void proj_hist(const float* __restrict__ means,
                                                 const float* __restrict__ covs,
                                                 float4* __restrict__ pl,
                                                 int* __restrict__ keys,
                                                 int* __restrict__ hist)
{
  int n = blockIdx.x * 256 + threadIdx.x;
  if (n >= NS) return;
  float m0 = means[3 * n], m1 = means[3 * n + 1], m2 = means[3 * n + 2];
  const float* C = covs + 9L * n;
  float c0 = C[0], c1 = C[1], c2 = C[2];
  float c3 = C[3], c4 = C[4], c5 = C[5];
  float c6 = C[6], c7 = C[7], c8 = C[8];
  #pragma unroll
  for (int v = 0; v < NV; ++v) {
    float p00 = c_P[v][0][0], p01 = c_P[v][0][1], p02 = c_P[v][0][2];
    float p10 = c_P[v][1][0], p11 = c_P[v][1][1], p12 = c_P[v][1][2];
    float cx = m0 * p00 + m1 * p01 + m2 * p02;
    float cy = m0 * p10 + m1 * p11 + m2 * p12;
    float t0 = c0 * p00 + c1 * p01 + c2 * p02;
    float t1 = c3 * p00 + c4 * p01 + c5 * p02;
    float t2 = c6 * p00 + c7 * p01 + c8 * p02;
    float s2x = p00 * t0 + p01 * t1 + p02 * t2;
    t0 = c0 * p10 + c1 * p11 + c2 * p12;
    t1 = c3 * p10 + c4 * p11 + c5 * p12;
    t2 = c6 * p10 + c7 * p11 + c8 * p12;
    float s2y = p10 * t0 + p11 * t1 + p12 * t2;
    float lx = 0.5f * log2f(fmaxf(s2x, 1e-20f)) + 9.0f;
    float ly = 0.5f * log2f(fmaxf(s2y, 1e-20f)) + 9.0f;
    lx = fminf(fmaxf(lx, 0.0f), 7.0f);
    ly = fminf(fmaxf(ly, 0.0f), 7.0f);
    pl[(long)v * NS + n] = make_float4(cx, cy, lx, ly);
    int l1f = (int)lx, l2f = (int)ly;
    int gx = min(max((int)((cx * 0.5f + 0.5f) * 32.0f), 0), 31);
    int gy = min(max((int)((cy * 0.5f + 0.5f) * 32.0f), 0), 31);
    int key = (((v * 8 + l1f) * 8 + l2f) * 32 + gy) * 32 + gx;
    keys[(long)v * NS + n] = key;
    atomicAdd(&hist[key], 1);
  }
}

// ---- scan stage 1: per-block exclusive scan of 1024, write block sums ----
__global__ __launch_bounds__(1024) void scan_block(int* __restrict__ hist,
                                                   int* __restrict__ bsum)
{
  __shared__ int s[1024];
  int tid = threadIdx.x, bid = blockIdx.x;
  int i = bid * 1024 + tid;
  int x = hist[i];
  s[tid] = x;
  __syncthreads();
  #pragma unroll
  for (int off = 1; off < 1024; off <<= 1) {
    int t = (tid >= off) ? s[tid - off] : 0;
    __syncthreads();
    s[tid] += t;
    __syncthreads();
  }
  hist[i] = s[tid] - x;              // exclusive
  if (tid == 1023) bsum[bid] = s[1023];
}

// ---- scan stage 2: exclusive scan of 640 block sums (single block) ----
__global__ __launch_bounds__(1024) void scan_top(int* __restrict__ bsum)
{
  __shared__ int s[1024];
  int tid = threadIdx.x;
  int x = (tid < 640) ? bsum[tid] : 0;
  s[tid] = x;
  __syncthreads();
  #pragma unroll
  for (int off = 1; off < 1024; off <<= 1) {
    int t = (tid >= off) ? s[tid - off] : 0;
    __syncthreads();
    s[tid] += t;
    __syncthreads();
  }
  if (tid < 640) bsum[tid] = s[tid] - x;
}

// ---- scan stage 3: add block base ----
__global__ __launch_bounds__(1024) void scan_add(int* __restrict__ hist,
                                                 const int* __restrict__ bsum)
{
  int i = blockIdx.x * 1024 + threadIdx.x;
  hist[i] += bsum[blockIdx.x];
}

// ---- scatter into sorted order ----
__global__ __launch_bounds__(256) void scatter(const float4* __restrict__ pl,
                                               const int* __restrict__ keys,
                                               int* __restrict__ hist,
                                               float4* __restrict__ spl,
                                               int* __restrict__ sidx)
{
  int p = blockIdx.x * 256 + threadIdx.x;   // p = v*NS + n
  if (p >= NV * NS) return;
  int k = keys[p];
  int pos = atomicAdd(&hist[k], 1);
  spl[pos] = pl[p];
  sidx[pos] = p & (NS - 1);
}

__device__ __forceinline__ void acc8(const __half* p, float w, float* acc) {
  uint4 d = *(const uint4*)p;
  const __half2* h = (const __half2*)&d;
  #pragma unroll
  for (int j = 0; j < 4; ++j) {
    float2 f = __half22float2(h[j]);
    acc[2 * j]     += w * f.x;
    acc[2 * j + 1] += w * f.y;
  }
}

// ---- interp over sorted pairs: 2 threads/pair, XCD-chunked swizzle ----
__global__ __launch_bounds__(256) void interp_sorted(const float4* __restrict__ spl,
                                                     const int* __restrict__ sidx,
                                                     const __half* __restrict__ pyr,
                                                     float* __restrict__ out)
{
  int bid = blockIdx.x;
  int swz = (bid & 7) * 2560 + (bid >> 3);    // 20480/8 = 2560 blocks per XCD
  int t = swz * 256 + threadIdx.x;
  int q = t & 1;
  int pos = t >> 1;                           // sorted pair index, v-major
  int v = pos >> 18;                          // NS = 2^18 pairs per vertex
  int n = sidx[pos];
  float4 p = spl[pos];
  float cx = p.x, cy = p.y, lx = p.z, ly = p.w;
  int l1f = (int)lx;
  int l2f = (int)ly;
  float wx = lx - (float)l1f;
  float wy = ly - (float)l2f;
  int l1c = (l1f < 7) ? l1f + 1 : 7;
  int l2c = (l2f < 7) ? l2f + 1 : 7;

  const __half* bvq = pyr + (long)v * PYR_PX * FD + q * 8;
  float acc[8] = {0.f, 0.f, 0.f, 0.f, 0.f, 0.f, 0.f, 0.f};

  #pragma unroll
  for (int i = 0; i < 2; ++i) {
    int l1 = i ? l1c : l1f;
    float wl1 = i ? wx : 1.0f - wx;
    int Wl = 512 >> l1;
    float u = (cx * 0.5f + 0.5f) * (float)Wl - 0.5f;
    float uf = floorf(u);
    float fu = u - uf;
    int iu = (int)uf;
    int ix0 = min(max(iu, 0), Wl - 1);
    int ix1 = min(max(iu + 1, 0), Wl - 1);
    #pragma unroll
    for (int j = 0; j < 2; ++j) {
      int l2 = j ? l2c : l2f;
      float wl2 = j ? wy : 1.0f - wy;
      int Hl = 512 >> l2;
      float vv = (cy * 0.5f + 0.5f) * (float)Hl - 0.5f;
      float vf = floorf(vv);
      float fv = vv - vf;
      int iv = (int)vf;
      int iy0 = min(max(iv, 0), Hl - 1);
      int iy1 = min(max(iv + 1, 0), Hl - 1);

      const __half* plane = bvq + offp(l1, l2) * FD;
      float w   = wl1 * wl2;
      float w00 = w * (1.0f - fu) * (1.0f - fv);
      float w10 = w * fu * (1.0f - fv);
      float w01 = w * (1.0f - fu) * fv;
      float w11 = w * fu * fv;

      acc8(plane + ((long)iy0 * Wl + ix0) * FD, w00, acc);
      acc8(plane + ((long)iy0 * Wl + ix1) * FD, w10, acc);
      acc8(plane + ((long)iy1 * Wl + ix0) * FD, w01, acc);
      acc8(plane + ((long)iy1 * Wl + ix1) * FD, w11, acc);
    }
  }

  float4* o = (float4*)(out + ((long)n * NV + v) * FD + q * 8);
  o[0] = make_float4(acc[0], acc[1], acc[2], acc[3]);
  o[1] = make_float4(acc[4], acc[5], acc[6], acc[7]);
}

extern "C" void kernel_launch(void* const* d_in, const int* in_sizes, int n_in,
                              void* d_out, int out_size, void* d_ws, size_t ws_size,
                              hipStream_t stream)
{
  const float* means = (const float*)d_in[0];
  const float* covs  = (const float*)d_in[1];
  const float* fm    = (const float*)d_in[2];
  float* out = (float*)d_out;
  char* ws = (char*)d_ws;
  __half* pyr  = (__half*)ws;
  float4* pl   = (float4*)(ws + OFF_PL);
  int*    keys = (int*)(ws + OFF_KEYS);
  int*    hist = (int*)(ws + OFF_HIST);
  int*    bsum = (int*)(ws + OFF_BSUM);
  float4* spl  = (float4*)(ws + OFF_SPL);
  int*    sidx = (int*)(ws + OFF_SIDX);

  build_w<<<NV * 512, 256, 0, stream>>>(fm, pyr);
  for (int l2 = 1; l2 <= 7; ++l2) {
    int total = NV * (512 >> l2) * 2040;
    pool_h<<<(total + 255) / 256, 256, 0, stream>>>(pyr, l2);
  }

  zero_hist<<<(NB_KEYS + 255) / 256, 256, 0, stream>>>(hist);
  proj_hist<<<NS / 256, 256, 0, stream>>>(means, covs, pl, keys, hist);
  scan_block<<<NB_KEYS / 1024, 1024, 0, stream>>>(hist, bsum);
  scan_top<<<1, 1024, 0, stream>>>(bsum);
  scan_add<<<NB_KEYS / 1024, 1024, 0, stream>>>(hist, bsum);
  scatter<<<(NV * NS) / 256, 256, 0, stream>>>(pl, keys, hist, spl, sidx);

  interp_sorted<<<20480, 256, 0, stream>>>(spl, sidx, pyr, out);
}

// Round 6
// 493.586 us; speedup vs baseline: 1.3554x; 1.3554x over previous
//
#include <hip/hip_runtime.h>
#include <hip/hip_fp16.h>

// RipEncoding, round 6: round-4 structure (no sort), interp = 1 thread/pair
// with all 16 taps issued as deep batched loads (latency-hiding via ILP).
//
// ws layout: [0, 332928000) fp16 pyramid (10 verts x 1020x1020 px x 16 halfs)
//            [332928000, +41943040) float4 proj table [v][n] = (cx,cy,lx,ly)

#define NV 10
#define FD 16
#define NS 262144          // 2^18
#define PYR_PX 1040400L    // 1020*1020 pixels per vertex
#define PYR_BYTES 332928000L

__constant__ float c_P[NV][2][3] = {
  {{-0.7071067811865476f, 0.7071067811865476f, 0.0f},
   {-0.4082482904638631f,-0.4082482904638631f, 0.8164965809277261f}},
  {{-0.7071067811865476f, 0.7071067811865476f, 0.0f},
   { 0.4082482904638631f, 0.4082482904638631f, 0.8164965809277261f}},
  {{ 0.7071067811865476f, 0.7071067811865476f, 0.0f},
   {-0.4082482904638631f, 0.4082482904638631f, 0.8164965809277261f}},
  {{ 0.7071067811865476f, 0.7071067811865476f, 0.0f},
   { 0.4082482904638631f,-0.4082482904638631f, 0.8164965809277261f}},
  {{-1.0f, 0.0f, 0.0f},
   { 0.0f,-0.3568220897730899f, 0.9341723589627157f}},
  {{-1.0f, 0.0f, 0.0f},
   { 0.0f, 0.3568220897730899f, 0.9341723589627157f}},
  {{ 0.0f, 1.0f, 0.0f},
   {-0.9341723589627157f, 0.0f, 0.3568220897730899f}},
  {{ 0.0f, 1.0f, 0.0f},
   { 0.9341723589627157f, 0.0f, 0.3568220897730899f}},
  {{-0.3568220897730899f, 0.9341723589627157f, 0.0f},
   { 0.0f, 0.0f, 1.0f}},
  {{ 0.3568220897730899f, 0.9341723589627157f, 0.0f},
   { 0.0f, 0.0f, 1.0f}},
};

__constant__ int c_CW[8] = {0, 512, 768, 896, 960, 992, 1008, 1016};

// pixel offset of plane (l1,l2) inside a vertex's pyramid (includes (0,0))
__device__ __forceinline__ long offp(int l1, int l2) {
  return 1020L * (long)c_CW[l1] + (long)(512 >> l1) * (long)c_CW[l2];
}

__device__ __forceinline__ uint2 pack4(float4 f) {
  __half2 h0 = __floats2half2_rn(f.x, f.y);
  __half2 h1 = __floats2half2_rn(f.z, f.w);
  uint2 s;
  s.x = *(unsigned int*)&h0;
  s.y = *(unsigned int*)&h1;
  return s;
}

// ---- pass 1: one block per (v, y) row; all 8 width levels from LDS ----
__global__ __launch_bounds__(256) void build_w(const float* __restrict__ fm,
                                               __half* __restrict__ pyr)
{
  __shared__ float4 lds[512 * 5];   // pixel p, quad fb at lds[p*5+fb]; 40 KB
  int b = blockIdx.x;
  int v = b >> 9, y = b & 511;
  int t = threadIdx.x;
  const float4* src = (const float4*)(fm + ((long)v * 262144L + (long)y * 512) * FD);
  #pragma unroll
  for (int i = 0; i < 8; ++i) {
    int u = t + 256 * i;                        // linear float4 index 0..2047
    float4 d = src[u];
    lds[(u >> 2) * 5 + (u & 3)] = d;
  }
  __syncthreads();
  __half* bv = pyr + (long)v * PYR_PX * FD;
  {                                             // level (0,0): convert row
    uint2* dst = (uint2*)(bv + (long)y * 512 * FD);
    #pragma unroll
    for (int i = 0; i < 8; ++i) {
      int u = t + 256 * i;
      dst[u] = pack4(lds[(u >> 2) * 5 + (u & 3)]);
    }
  }
  #pragma unroll
  for (int l1 = 1; l1 <= 7; ++l1) {
    int W = 512 >> l1;
    int units = W * 4;
    float4 r[4];
    #pragma unroll
    for (int i = 0; i < 4; ++i) {
      int u = t + 256 * i;
      if (u < units) {
        int px = u >> 2, fb = u & 3;
        float4 a = lds[(2 * px) * 5 + fb];
        float4 c = lds[(2 * px + 1) * 5 + fb];
        r[i].x = 0.5f * (a.x + c.x); r[i].y = 0.5f * (a.y + c.y);
        r[i].z = 0.5f * (a.z + c.z); r[i].w = 0.5f * (a.w + c.w);
      }
    }
    __syncthreads();
    uint2* dst = (uint2*)(bv + (offp(l1, 0) + (long)y * W) * FD);
    #pragma unroll
    for (int i = 0; i < 4; ++i) {
      int u = t + 256 * i;
      if (u < units) {
        int px = u >> 2, fb = u & 3;
        lds[px * 5 + fb] = r[i];
        dst[u] = pack4(r[i]);
      }
    }
    __syncthreads();
  }
}

// ---- pass 2: per-level height pool, fully coalesced (7 launches) ----
__global__ __launch_bounds__(256) void pool_h(__half* __restrict__ pyr, int l2)
{
  int H = 512 >> l2;
  int total = NV * H * 2040;          // units: 1020 px * 2 slots per virtual row
  int t = blockIdx.x * 256 + threadIdx.x;
  if (t >= total) return;
  int u = t % 2040;
  int r2 = t / 2040;
  int c = u >> 1, k = u & 1;          // virtual column, 16B slot
  int y = r2 & (H - 1);
  int v = r2 >> (9 - l2);
  int l1 = 0;
  #pragma unroll
  for (int i = 1; i < 8; ++i) l1 += (c >= c_CW[i]) ? 1 : 0;
  int x = c - c_CW[l1];
  int W = 512 >> l1;
  __half* bv = pyr + (long)v * PYR_PX * FD;
  const __half* src = bv + offp(l1, l2 - 1) * FD;
  uint4 a = *(const uint4*)(src + ((long)(2 * y) * W + x) * FD + k * 8);
  uint4 b = *(const uint4*)(src + ((long)(2 * y + 1) * W + x) * FD + k * 8);
  const __half2* ha = (const __half2*)&a;
  const __half2* hb = (const __half2*)&b;
  uint4 res;
  __half2* hr = (__half2*)&res;
  #pragma unroll
  for (int j = 0; j < 4; ++j) {
    float2 fa = __half22float2(ha[j]);
    float2 fb = __half22float2(hb[j]);
    hr[j] = __floats2half2_rn(0.5f * (fa.x + fb.x), 0.5f * (fa.y + fb.y));
  }
  *(uint4*)(bv + offp(l1, l2) * FD + ((long)y * W + x) * FD + k * 8) = res;
}

// ---- projection/level precompute: one thread per sample ----
__global__ __launch_bounds__(256) void proj_kernel(const float* __restrict__ means,
                                                   const float* __restrict__ covs,
                                                   float4* __restrict__ pl)
{
  int n = blockIdx.x * 256 + threadIdx.x;
  if (n >= NS) return;
  float m0 = means[3 * n], m1 = means[3 * n + 1], m2 = means[3 * n + 2];
  const float* C = covs + 9L * n;
  float c0 = C[0], c1 = C[1], c2 = C[2];
  float c3 = C[3], c4 = C[4], c5 = C[5];
  float c6 = C[6], c7 = C[7], c8 = C[8];
  #pragma unroll
  for (int v = 0; v < NV; ++v) {
    float p00 = c_P[v][0][0], p01 = c_P[v][0][1], p02 = c_P[v][0][2];
    float p10 = c_P[v][1][0], p11 = c_P[v][1][1], p12 = c_P[v][1][2];
    float cx = m0 * p00 + m1 * p01 + m2 * p02;
    float cy = m0 * p10 + m1 * p11 + m2 * p12;
    float t0 = c0 * p00 + c1 * p01 + c2 * p02;
    float t1 = c3 * p00 + c4 * p01 + c5 * p02;
    float t2 = c6 * p00 + c7 * p01 + c8 * p02;
    float s2x = p00 * t0 + p01 * t1 + p02 * t2;
    t0 = c0 * p10 + c1 * p11 + c2 * p12;
    t1 = c3 * p10 + c4 * p11 + c5 * p12;
    t2 = c6 * p10 + c7 * p11 + c8 * p12;
    float s2y = p10 * t0 + p11 * t1 + p12 * t2;
    float lx = 0.5f * log2f(fmaxf(s2x, 1e-20f)) + 9.0f;
    float ly = 0.5f * log2f(fmaxf(s2y, 1e-20f)) + 9.0f;
    lx = fminf(fmaxf(lx, 0.0f), 7.0f);
    ly = fminf(fmaxf(ly, 0.0f), 7.0f);
    pl[(long)v * NS + n] = make_float4(cx, cy, lx, ly);
  }
}

// ---- interp: 1 thread per (n,v) pair, 16 taps batch-issued ----
// thread t = v2*2^19 + n*2 + vlow ; v = 2*v2 + vlow (adjacent threads ->
// adjacent 64B output chunks). grid = 10240 blocks (bijective XCD chunking).
__global__ void interp1(const float4* __restrict__ pl,
                        const __half* __restrict__ pyr,
                        float* __restrict__ out)
{
  int bid = blockIdx.x;
  int swz = (bid & 7) * 1280 + (bid >> 3);    // 10240/8 = 1280 blocks per XCD
  int t = swz * 256 + threadIdx.x;
  int vlow = t & 1;
  int n = (t >> 1) & (NS - 1);
  int v2 = t >> 19;
  int v = v2 * 2 + vlow;

  float4 p = pl[(long)v * NS + n];
  float cx = p.x, cy = p.y, lx = p.z, ly = p.w;
  int l1f = (int)lx;                 // lx,ly already clipped to [0,7]
  int l2f = (int)ly;
  float wx = lx - (float)l1f;
  float wy = ly - (float)l2f;
  int l1c = (l1f < 7) ? l1f + 1 : 7;
  int l2c = (l2f < 7) ? l2f + 1 : 7;

  const __half* bv = pyr + (long)v * PYR_PX * FD;

  // Phase 1: all 16 tap addresses + weights.
  const __half* addr[16];
  float wt[16];
  #pragma unroll
  for (int i = 0; i < 2; ++i) {
    int l1 = i ? l1c : l1f;
    float wl1 = i ? wx : 1.0f - wx;
    int Wl = 512 >> l1;
    float u = (cx * 0.5f + 0.5f) * (float)Wl - 0.5f;
    float uf = floorf(u);
    float fu = u - uf;
    int iu = (int)uf;
    int ix0 = min(max(iu, 0), Wl - 1);
    int ix1 = min(max(iu + 1, 0), Wl - 1);
    #pragma unroll
    for (int j = 0; j < 2; ++j) {
      int l2 = j ? l2c : l2f;
      float wl2 = j ? wy : 1.0f - wy;
      int Hl = 512 >> l2;
      float vv = (cy * 0.5f + 0.5f) * (float)Hl - 0.5f;
      float vf = floorf(vv);
      float fv = vv - vf;
      int iv = (int)vf;
      int iy0 = min(max(iv, 0), Hl - 1);
      int iy1 = min(max(iv + 1, 0), Hl - 1);

      const __half* plane = bv + offp(l1, l2) * FD;
      float w = wl1 * wl2;
      int k = (i * 2 + j) * 4;
      addr[k + 0] = plane + ((long)iy0 * Wl + ix0) * FD;
      addr[k + 1] = plane + ((long)iy0 * Wl + ix1) * FD;
      addr[k + 2] = plane + ((long)iy1 * Wl + ix0) * FD;
      addr[k + 3] = plane + ((long)iy1 * Wl + ix1) * FD;
      wt[k + 0] = w * (1.0f - fu) * (1.0f - fv);
      wt[k + 1] = w * fu * (1.0f - fv);
      wt[k + 2] = w * (1.0f - fu) * fv;
      wt[k + 3] = w * fu * fv;
    }
  }

  float acc[16];
  #pragma unroll
  for (int f = 0; f < 16; ++f) acc[f] = 0.f;

  // Phase 2+3: two batches of 8 taps; each batch issues 16 dwordx4 loads
  // before any accumulation (deep ILP for latency hiding).
  #pragma unroll
  for (int h = 0; h < 2; ++h) {
    uint4 da[8], db[8];
    #pragma unroll
    for (int k = 0; k < 8; ++k) {
      const uint4* q = (const uint4*)addr[h * 8 + k];
      da[k] = q[0];
      db[k] = q[1];
    }
    #pragma unroll
    for (int k = 0; k < 8; ++k) {
      float w = wt[h * 8 + k];
      const __half2* h0 = (const __half2*)&da[k];
      const __half2* h1 = (const __half2*)&db[k];
      #pragma unroll
      for (int j = 0; j < 4; ++j) {
        float2 f0 = __half22float2(h0[j]);
        float2 f1 = __half22float2(h1[j]);
        acc[2 * j]      += w * f0.x;
        acc[2 * j + 1]  += w * f0.y;
        acc[8 + 2 * j]     += w * f1.x;
        acc[8 + 2 * j + 1] += w * f1.y;
      }
    }
  }

  float4* o = (float4*)(out + ((long)n * NV + v) * FD);
  o[0] = make_float4(acc[0],  acc[1],  acc[2],  acc[3]);
  o[1] = make_float4(acc[4],  acc[5],  acc[6],  acc[7]);
  o[2] = make_float4(acc[8],  acc[9],  acc[10], acc[11]);
  o[3] = make_float4(acc[12], acc[13], acc[14], acc[15]);
}

extern "C" void kernel_launch(void* const* d_in, const int* in_sizes, int n_in,
                              void* d_out, int out_size, void* d_ws, size_t ws_size,
                              hipStream_t stream)
{
  const float* means = (const float*)d_in[0];
  const float* covs  = (const float*)d_in[1];
  const float* fm    = (const float*)d_in[2];
  float* out = (float*)d_out;
  __half* pyr = (__half*)d_ws;
  float4* pl  = (float4*)((char*)d_ws + PYR_BYTES);

  build_w<<<NV * 512, 256, 0, stream>>>(fm, pyr);
  for (int l2 = 1; l2 <= 7; ++l2) {
    int total = NV * (512 >> l2) * 2040;
    pool_h<<<(total + 255) / 256, 256, 0, stream>>>(pyr, l2);
  }
  proj_kernel<<<(NS + 255) / 256, 256, 0, stream>>>(means, covs, pl);

  interp1<<<10240, 256, 0, stream>>>(pl, pyr, out);
}

// Round 7
// 315.780 us; speedup vs baseline: 2.1187x; 1.5631x over previous
//
#include <hip/hip_runtime.h>
#include <hip/hip_fp16.h>

// RipEncoding, round 7: fp16 pyramid + 4-threads-per-pair cooperative row
// loads (64B per tap-row in one instruction, weight-folded x-clamp).
//
// ws layout: [0, 332928000) fp16 pyramid (10 verts x 1020x1020 px x 16 halfs)
//            [332928000, +41943040) float4 proj table [v][n] = (cx,cy,lx,ly)

#define NV 10
#define FD 16
#define NS 262144          // 2^18
#define PYR_PX 1040400L    // 1020*1020 pixels per vertex
#define PYR_BYTES 332928000L

__constant__ float c_P[NV][2][3] = {
  {{-0.7071067811865476f, 0.7071067811865476f, 0.0f},
   {-0.4082482904638631f,-0.4082482904638631f, 0.8164965809277261f}},
  {{-0.7071067811865476f, 0.7071067811865476f, 0.0f},
   { 0.4082482904638631f, 0.4082482904638631f, 0.8164965809277261f}},
  {{ 0.7071067811865476f, 0.7071067811865476f, 0.0f},
   {-0.4082482904638631f, 0.4082482904638631f, 0.8164965809277261f}},
  {{ 0.7071067811865476f, 0.7071067811865476f, 0.0f},
   { 0.4082482904638631f,-0.4082482904638631f, 0.8164965809277261f}},
  {{-1.0f, 0.0f, 0.0f},
   { 0.0f,-0.3568220897730899f, 0.9341723589627157f}},
  {{-1.0f, 0.0f, 0.0f},
   { 0.0f, 0.3568220897730899f, 0.9341723589627157f}},
  {{ 0.0f, 1.0f, 0.0f},
   {-0.9341723589627157f, 0.0f, 0.3568220897730899f}},
  {{ 0.0f, 1.0f, 0.0f},
   { 0.9341723589627157f, 0.0f, 0.3568220897730899f}},
  {{-0.3568220897730899f, 0.9341723589627157f, 0.0f},
   { 0.0f, 0.0f, 1.0f}},
  {{ 0.3568220897730899f, 0.9341723589627157f, 0.0f},
   { 0.0f, 0.0f, 1.0f}},
};

__constant__ int c_CW[8] = {0, 512, 768, 896, 960, 992, 1008, 1016};

// pixel offset of plane (l1,l2) inside a vertex's pyramid (includes (0,0))
__device__ __forceinline__ long offp(int l1, int l2) {
  return 1020L * (long)c_CW[l1] + (long)(512 >> l1) * (long)c_CW[l2];
}

__device__ __forceinline__ uint2 pack4(float4 f) {
  __half2 h0 = __floats2half2_rn(f.x, f.y);
  __half2 h1 = __floats2half2_rn(f.z, f.w);
  uint2 s;
  s.x = *(unsigned int*)&h0;
  s.y = *(unsigned int*)&h1;
  return s;
}

// ---- pass 1: one block per (v, y) row; all 8 width levels from LDS ----
__global__ __launch_bounds__(256) void build_w(const float* __restrict__ fm,
                                               __half* __restrict__ pyr)
{
  __shared__ float4 lds[512 * 5];   // pixel p, quad fb at lds[p*5+fb]; 40 KB
  int b = blockIdx.x;
  int v = b >> 9, y = b & 511;
  int t = threadIdx.x;
  const float4* src = (const float4*)(fm + ((long)v * 262144L + (long)y * 512) * FD);
  #pragma unroll
  for (int i = 0; i < 8; ++i) {
    int u = t + 256 * i;                        // linear float4 index 0..2047
    float4 d = src[u];
    lds[(u >> 2) * 5 + (u & 3)] = d;
  }
  __syncthreads();
  __half* bv = pyr + (long)v * PYR_PX * FD;
  {                                             // level (0,0): convert row
    uint2* dst = (uint2*)(bv + (long)y * 512 * FD);
    #pragma unroll
    for (int i = 0; i < 8; ++i) {
      int u = t + 256 * i;
      dst[u] = pack4(lds[(u >> 2) * 5 + (u & 3)]);
    }
  }
  #pragma unroll
  for (int l1 = 1; l1 <= 7; ++l1) {
    int W = 512 >> l1;
    int units = W * 4;
    float4 r[4];
    #pragma unroll
    for (int i = 0; i < 4; ++i) {
      int u = t + 256 * i;
      if (u < units) {
        int px = u >> 2, fb = u & 3;
        float4 a = lds[(2 * px) * 5 + fb];
        float4 c = lds[(2 * px + 1) * 5 + fb];
        r[i].x = 0.5f * (a.x + c.x); r[i].y = 0.5f * (a.y + c.y);
        r[i].z = 0.5f * (a.z + c.z); r[i].w = 0.5f * (a.w + c.w);
      }
    }
    __syncthreads();
    uint2* dst = (uint2*)(bv + (offp(l1, 0) + (long)y * W) * FD);
    #pragma unroll
    for (int i = 0; i < 4; ++i) {
      int u = t + 256 * i;
      if (u < units) {
        int px = u >> 2, fb = u & 3;
        lds[px * 5 + fb] = r[i];
        dst[u] = pack4(r[i]);
      }
    }
    __syncthreads();
  }
}

// ---- pass 2: per-level height pool, fully coalesced (7 launches) ----
__global__ __launch_bounds__(256) void pool_h(__half* __restrict__ pyr, int l2)
{
  int H = 512 >> l2;
  int total = NV * H * 2040;          // units: 1020 px * 2 slots per virtual row
  int t = blockIdx.x * 256 + threadIdx.x;
  if (t >= total) return;
  int u = t % 2040;
  int r2 = t / 2040;
  int c = u >> 1, k = u & 1;          // virtual column, 16B slot
  int y = r2 & (H - 1);
  int v = r2 >> (9 - l2);
  int l1 = 0;
  #pragma unroll
  for (int i = 1; i < 8; ++i) l1 += (c >= c_CW[i]) ? 1 : 0;
  int x = c - c_CW[l1];
  int W = 512 >> l1;
  __half* bv = pyr + (long)v * PYR_PX * FD;
  const __half* src = bv + offp(l1, l2 - 1) * FD;
  uint4 a = *(const uint4*)(src + ((long)(2 * y) * W + x) * FD + k * 8);
  uint4 b = *(const uint4*)(src + ((long)(2 * y + 1) * W + x) * FD + k * 8);
  const __half2* ha = (const __half2*)&a;
  const __half2* hb = (const __half2*)&b;
  uint4 res;
  __half2* hr = (__half2*)&res;
  #pragma unroll
  for (int j = 0; j < 4; ++j) {
    float2 fa = __half22float2(ha[j]);
    float2 fb = __half22float2(hb[j]);
    hr[j] = __floats2half2_rn(0.5f * (fa.x + fb.x), 0.5f * (fa.y + fb.y));
  }
  *(uint4*)(bv + offp(l1, l2) * FD + ((long)y * W + x) * FD + k * 8) = res;
}

// ---- projection/level precompute: one thread per sample ----
__global__ __launch_bounds__(256) void proj_kernel(const float* __restrict__ means,
                                                   const float* __restrict__ covs,
                                                   float4* __restrict__ pl)
{
  int n = blockIdx.x * 256 + threadIdx.x;
  if (n >= NS) return;
  float m0 = means[3 * n], m1 = means[3 * n + 1], m2 = means[3 * n + 2];
  const float* C = covs + 9L * n;
  float c0 = C[0], c1 = C[1], c2 = C[2];
  float c3 = C[3], c4 = C[4], c5 = C[5];
  float c6 = C[6], c7 = C[7], c8 = C[8];
  #pragma unroll
  for (int v = 0; v < NV; ++v) {
    float p00 = c_P[v][0][0], p01 = c_P[v][0][1], p02 = c_P[v][0][2];
    float p10 = c_P[v][1][0], p11 = c_P[v][1][1], p12 = c_P[v][1][2];
    float cx = m0 * p00 + m1 * p01 + m2 * p02;
    float cy = m0 * p10 + m1 * p11 + m2 * p12;
    float t0 = c0 * p00 + c1 * p01 + c2 * p02;
    float t1 = c3 * p00 + c4 * p01 + c5 * p02;
    float t2 = c6 * p00 + c7 * p01 + c8 * p02;
    float s2x = p00 * t0 + p01 * t1 + p02 * t2;
    t0 = c0 * p10 + c1 * p11 + c2 * p12;
    t1 = c3 * p10 + c4 * p11 + c5 * p12;
    t2 = c6 * p10 + c7 * p11 + c8 * p12;
    float s2y = p10 * t0 + p11 * t1 + p12 * t2;
    float lx = 0.5f * log2f(fmaxf(s2x, 1e-20f)) + 9.0f;
    float ly = 0.5f * log2f(fmaxf(s2y, 1e-20f)) + 9.0f;
    lx = fminf(fmaxf(lx, 0.0f), 7.0f);
    ly = fminf(fmaxf(ly, 0.0f), 7.0f);
    pl[(long)v * NS + n] = make_float4(cx, cy, lx, ly);
  }
}

// ---- interp: 4 threads/pair, cooperative 64B row loads ----
// lane q: pixel (q&1) of the speculative (ix0, ix0+1) span, feature-half
// (q>>1). Per combo: 2 loads (rows iy0, iy1). x-clamp folded into weights.
// thread t = ((v2*NS + n)*2 + vlow)*4 + q ; v = 2*v2+vlow.
__global__ __launch_bounds__(256, 4) void interp4(const float4* __restrict__ pl,
                                                  const __half* __restrict__ pyr,
                                                  float* __restrict__ out)
{
  int bid = blockIdx.x;
  int swz = (bid & 7) * 5120 + (bid >> 3);    // 40960/8 = 5120 blocks per XCD
  int t = swz * 256 + threadIdx.x;
  int q = t & 3;
  int vlow = (t >> 2) & 1;
  int n = (t >> 3) & (NS - 1);
  int v2 = t >> 21;
  int v = v2 * 2 + vlow;

  float4 p = pl[(long)v * NS + n];
  float cx = p.x, cy = p.y, lx = p.z, ly = p.w;
  int l1f = (int)lx;                 // lx,ly already clipped to [0,7]
  int l2f = (int)ly;
  float wx = lx - (float)l1f;
  float wy = ly - (float)l2f;
  int l1c = (l1f < 7) ? l1f + 1 : 7;
  int l2c = (l2f < 7) ? l2f + 1 : 7;

  // lane byte-slot inside a 64B row span: pixel (q&1), half (q>>1)
  const __half* bv = pyr + (long)v * PYR_PX * FD + ((q & 1) * 16 + (q >> 1) * 8);

  const __half* a0[4];
  const __half* a1[4];
  float w0[4], w1[4];

  #pragma unroll
  for (int cb = 0; cb < 4; ++cb) {
    int l1 = (cb & 2) ? l1c : l1f;
    float wla = (cb & 2) ? wx : 1.0f - wx;
    int l2 = (cb & 1) ? l2c : l2f;
    float wlb = (cb & 1) ? wy : 1.0f - wy;
    int Wl = 512 >> l1, Hl = 512 >> l2;

    float u = (cx * 0.5f + 0.5f) * (float)Wl - 0.5f;
    float uf = floorf(u);
    float fu = u - uf;
    int iu = (int)uf;
    int ix0 = min(max(iu, 0), Wl - 1);
    int ix1 = min(max(iu + 1, 0), Wl - 1);

    float vv = (cy * 0.5f + 0.5f) * (float)Hl - 0.5f;
    float vf = floorf(vv);
    float fv = vv - vf;
    int iv = (int)vf;
    int iy0 = min(max(iv, 0), Hl - 1);
    int iy1 = min(max(iv + 1, 0), Hl - 1);

    const __half* base = bv + offp(l1, l2) * FD;
    a0[cb] = base + ((long)iy0 * Wl + ix0) * FD;
    a1[cb] = base + ((long)iy1 * Wl + ix0) * FD;

    bool edge = (ix1 == ix0);                    // x clamped (left or right)
    float wxl = (q & 1) ? (edge ? 0.0f : fu)     // speculative pixel ix0+1
                        : (edge ? 1.0f : 1.0f - fu);
    float wb = wla * wlb * wxl;
    w0[cb] = wb * (1.0f - fv);
    w1[cb] = wb * fv;
  }

  // batch-issue all 8 row loads (independent, deep in flight)
  uint4 d0[4], d1[4];
  #pragma unroll
  for (int cb = 0; cb < 4; ++cb) {
    d0[cb] = *(const uint4*)a0[cb];
    d1[cb] = *(const uint4*)a1[cb];
  }

  float acc[8] = {0.f, 0.f, 0.f, 0.f, 0.f, 0.f, 0.f, 0.f};
  #pragma unroll
  for (int cb = 0; cb < 4; ++cb) {
    const __half2* h0 = (const __half2*)&d0[cb];
    const __half2* h1 = (const __half2*)&d1[cb];
    #pragma unroll
    for (int j = 0; j < 4; ++j) {
      float2 f0 = __half22float2(h0[j]);
      float2 f1 = __half22float2(h1[j]);
      acc[2 * j]     += w0[cb] * f0.x + w1[cb] * f1.x;
      acc[2 * j + 1] += w0[cb] * f0.y + w1[cb] * f1.y;
    }
  }

  // combine the two pixels of the bilinear x-span (lanes q and q^1)
  #pragma unroll
  for (int j = 0; j < 8; ++j) acc[j] += __shfl_xor(acc[j], 1);

  // lane q writes features [4q, 4q+4): q&1 selects upper half of this
  // lane's 8 accumulated features (see mapping in header comment)
  float4 o = (q & 1) ? make_float4(acc[4], acc[5], acc[6], acc[7])
                     : make_float4(acc[0], acc[1], acc[2], acc[3]);
  *(float4*)(out + ((long)n * NV + v) * FD + q * 4) = o;
}

extern "C" void kernel_launch(void* const* d_in, const int* in_sizes, int n_in,
                              void* d_out, int out_size, void* d_ws, size_t ws_size,
                              hipStream_t stream)
{
  const float* means = (const float*)d_in[0];
  const float* covs  = (const float*)d_in[1];
  const float* fm    = (const float*)d_in[2];
  float* out = (float*)d_out;
  __half* pyr = (__half*)d_ws;
  float4* pl  = (float4*)((char*)d_ws + PYR_BYTES);

  build_w<<<NV * 512, 256, 0, stream>>>(fm, pyr);
  for (int l2 = 1; l2 <= 7; ++l2) {
    int total = NV * (512 >> l2) * 2040;
    pool_h<<<(total + 255) / 256, 256, 0, stream>>>(pyr, l2);
  }
  proj_kernel<<<(NS + 255) / 256, 256, 0, stream>>>(means, covs, pl);

  interp4<<<40960, 256, 0, stream>>>(pl, pyr, out);
}